// Round 5
// baseline (406.458 us; speedup 1.0000x reference)
//
#include <hip/hip_runtime.h>
#include <stdint.h>

// W8A8 int8 GEMM + dequant epilogue, MI355X gfx950.
// R11: counted-vmcnt with TRUE 2-tile aging + 2 blocks/CU + proven swizzle.
// R6/R7/R10 all drain vmcnt(0) per tile (m218: drain0 kills the pipeline);
// R8/R9 had counted vmcnt but a conflicted BK=64 swizzle. This round:
// BM=BN=128, BK=128, 256 thr (4 waves 2x2, wave 64x64, acc 2x2 of 32x32).
// LDS = 2 x (16K A + 16K B) = 64 KiB -> 2 blocks/CU. 8 stage-issues/tile;
// steady-state s_waitcnt vmcnt(8) waits only for loads issued TWO tiles ago
// (~9K cyc aged -> no wait); never vmcnt(0) in main loop; 2 raw barriers
// per tile, no intra-tile barriers (compiler schedules reads ahead of MFMA).
// BK=128 8-chunk XOR swizzle, measured conflict-free in R3/R5/R6/R10.
// out[m,n] = (sum_k A*W + sum_input[m]*zp_w[n]) * si[m]*sw[n] + bias[n]

#define BM 128
#define BN 128
#define BK 128

typedef __attribute__((ext_vector_type(4))) int int32x4;
typedef __attribute__((ext_vector_type(16))) int int32x16;

__device__ __forceinline__ void async_copy16(const uint8_t* g, uint8_t* l) {
  __builtin_amdgcn_global_load_lds(
      (const __attribute__((address_space(1))) uint32_t*)(const void*)g,
      (__attribute__((address_space(3))) uint32_t*)l,
      16, 0, 0);
}

// Coalesced pack, grid-stride: one int32x4 (4 int8-as-int32) -> one uint32.
__global__ __launch_bounds__(256) void pack_kernel(
    const int* __restrict__ A, const int* __restrict__ B,
    uint8_t* __restrict__ A8, uint8_t* __restrict__ B8,
    int nA4, int nTot4) {
  const int stride = gridDim.x * blockDim.x;
  for (int t = blockIdx.x * blockDim.x + threadIdx.x; t < nTot4; t += stride) {
    const int32x4* src;
    uint32_t* dst;
    if (t < nA4) {
      src = (const int32x4*)A + t;
      dst = (uint32_t*)A8 + t;
    } else {
      int u = t - nA4;
      src = (const int32x4*)B + u;
      dst = (uint32_t*)B8 + u;
    }
    int32x4 v = __builtin_nontemporal_load(src);  // read-once stream
    *dst = (uint32_t)(v.x & 255) | ((uint32_t)(v.y & 255) << 8) |
           ((uint32_t)(v.z & 255) << 16) | ((uint32_t)(v.w & 255) << 24);
  }
}

// Stage one 128x128 A tile (4 issues) + 128x128 B tile (4 issues).
// Thread: row_s = tid>>3 (0..31), slot cs = tid&7, global chunk
// cg = cs ^ ((tid>>4)&7); issue p covers rows [p*32, p*32+32).
// Invariant: LDS row r (128 B) slot cs holds global chunk cs ^ ((r>>1)&7).
__device__ __forceinline__ void stage_tile(
    const uint8_t* Ab, const uint8_t* Bb, size_t sK, int k0,
    uint8_t* AsBuf, uint8_t* BsBuf, int ldst) {
#pragma unroll
  for (int p = 0; p < 4; ++p)
    async_copy16(Ab + (size_t)(p * 32) * sK + k0, AsBuf + p * 4096 + ldst);
#pragma unroll
  for (int p = 0; p < 4; ++p)
    async_copy16(Bb + (size_t)(p * 32) * sK + k0, BsBuf + p * 4096 + ldst);
}

__global__ __launch_bounds__(256, 2) void w8a8_gemm(
    const uint8_t* __restrict__ A8, const uint8_t* __restrict__ B8,
    const float* __restrict__ bias,
    const float* __restrict__ s_in,
    const float* __restrict__ s_w,
    const float* __restrict__ sum_in,
    const int* __restrict__ zp_w,
    float* __restrict__ out,
    int M, int N, int K) {
  __shared__ uint8_t As[2][BM * BK];  // 2 x 16 KiB
  __shared__ uint8_t Bs[2][BN * BK];  // 2 x 16 KiB  -> 64 KiB total

  const int tid = threadIdx.x;
  const int bm = blockIdx.y, bn = blockIdx.x;  // plain 2D grid (best FETCH)
  const int row0 = bm * BM, col0 = bn * BN;

  const int wave = tid >> 6, lane = tid & 63;
  const int m32 = lane & 31, half = lane >> 5;
  const int wm = (wave >> 1) * 64;  // 2 wave-rows of 64
  const int wn = (wave & 1) * 64;   // 2 wave-cols of 64
  const size_t sK = (size_t)K;

  // staging geometry (see stage_tile comment)
  const int row_s = tid >> 3;                   // 0..31
  const int cg = (tid & 7) ^ ((tid >> 4) & 7);
  const int ldst = tid * 16;

  const uint8_t* Ab = A8 + (size_t)(row0 + row_s) * sK + cg * 16;
  const uint8_t* Bb = B8 + (size_t)(col0 + row_s) * sK + cg * 16;

  int32x16 acc[2][2] = {};

  const int NT = K / BK;
  // Prologue: 16 loads/thread in flight (tiles 0 and 1).
  stage_tile(Ab, Bb, sK, 0, &As[0][0], &Bs[0][0], ldst);
  stage_tile(Ab, Bb, sK, BK, &As[1][0], &Bs[1][0], ldst);

  int cur = 0;
  const int swzr = (m32 >> 1) & 7;
  for (int kt = 0; kt < NT; ++kt) {
    // Tile kt's 8 loads (issued 2 tiles ago) land; kt+1's 8 stay in flight.
    if (kt + 1 < NT) {
      asm volatile("s_waitcnt vmcnt(8)" ::: "memory");
    } else {
      asm volatile("s_waitcnt vmcnt(0)" ::: "memory");
    }
    __builtin_amdgcn_s_barrier();

    const uint8_t* Ac = &As[cur][0];
    const uint8_t* Bc = &Bs[cur][0];
    // No intra-tile barriers: compiler hoists ds_reads across MFMAs,
    // fine-grained lgkmcnt; LDS pipe (~16% of MFMA cyc) overlaps freely.
#pragma unroll
    for (int ks = 0; ks < 4; ++ks) {
      const int gran = ((ks * 2 + half) ^ swzr) * 16;
      int32x4 afrag[2], bfrag[2];
#pragma unroll
      for (int i = 0; i < 2; ++i)
        afrag[i] = *(const int32x4*)&Ac[(wm + i * 32 + m32) * BK + gran];
#pragma unroll
      for (int j = 0; j < 2; ++j)
        bfrag[j] = *(const int32x4*)&Bc[(wn + j * 32 + m32) * BK + gran];
#pragma unroll
      for (int i = 0; i < 2; ++i)
#pragma unroll
        for (int j = 0; j < 2; ++j)
          acc[i][j] = __builtin_amdgcn_mfma_i32_32x32x32_i8(
              afrag[i], bfrag[j], acc[i][j], 0, 0, 0);
    }
    // Our ds_reads of buf[cur] must retire before restaging overwrites it.
    asm volatile("s_waitcnt lgkmcnt(0)" ::: "memory");
    __builtin_amdgcn_s_barrier();
    if (kt + 2 < NT)
      stage_tile(Ab, Bb, sK, (kt + 2) * BK, &As[cur][0], &Bs[cur][0], ldst);
    cur ^= 1;
  }

  // Epilogue: 32x32 C/D layout col=lane&31, row=(reg&3)+8*(reg>>2)+4*(lane>>5).
  float swj[2], zpj[2], bj[2];
#pragma unroll
  for (int j = 0; j < 2; ++j) {
    int gc = col0 + wn + j * 32 + m32;
    swj[j] = s_w[gc];
    zpj[j] = (float)zp_w[gc];
    bj[j] = bias[gc];
  }
#pragma unroll
  for (int i = 0; i < 2; ++i) {
#pragma unroll
    for (int reg = 0; reg < 16; ++reg) {
      int gr = row0 + wm + i * 32 + (reg & 3) + 8 * (reg >> 2) + 4 * half;
      float siv = s_in[gr];
      float suv = sum_in[gr];
      float* orow = out + (size_t)gr * N + col0 + wn + m32;
#pragma unroll
      for (int j = 0; j < 2; ++j) {
        float v = ((float)acc[i][j][reg] + suv * zpj[j]) * (siv * swj[j]) + bj[j];
        __builtin_nontemporal_store(v, &orow[j * 32]);
      }
    }
  }
}

// Fallback (ws too small): unpacked int32 inputs, BK=64, VALU pack + ds_write.
__global__ __launch_bounds__(256) void w8a8_gemm_fallback(
    const int* __restrict__ A32, const int* __restrict__ B32,
    const float* __restrict__ bias,
    const float* __restrict__ s_in,
    const float* __restrict__ s_w,
    const float* __restrict__ sum_in,
    const int* __restrict__ zp_w,
    float* __restrict__ out,
    int M, int N, int K) {
  __shared__ uint8_t As[128 * 64];
  __shared__ uint8_t Bs[128 * 64];
  const int tid = threadIdx.x;
  const int bm = blockIdx.y, bn = blockIdx.x;
  const int row0 = bm * 128, col0 = bn * 128;
  const int wave = tid >> 6, lane = tid & 63;
  const int quad = lane >> 4, r = lane & 15;
  const int wm = (wave >> 1) * 64, wn = (wave & 1) * 64;
  const int lin = tid * 16;
  const int srow = lin >> 6;
  const int scol = lin & 63;
  const size_t sK = (size_t)K;
  int32x4 acc[4][4] = {};
  for (int k0 = 0; k0 < K; k0 += 64) {
#pragma unroll
    for (int c = 0; c < 2; ++c) {
      const int* ag = A32 + (size_t)(row0 + srow + c * 64) * sK + k0 + scol;
      const int* bg = B32 + (size_t)(col0 + srow + c * 64) * sK + k0 + scol;
      int32x4 pa, pb;
#pragma unroll
      for (int q = 0; q < 4; ++q) {
        int4 va = ((const int4*)ag)[q];
        int4 vb = ((const int4*)bg)[q];
        pa[q] = (int)((uint32_t)(va.x & 255) | ((uint32_t)(va.y & 255) << 8) |
                      ((uint32_t)(va.z & 255) << 16) | ((uint32_t)(va.w & 255) << 24));
        pb[q] = (int)((uint32_t)(vb.x & 255) | ((uint32_t)(vb.y & 255) << 8) |
                      ((uint32_t)(vb.z & 255) << 16) | ((uint32_t)(vb.w & 255) << 24));
      }
      *(int32x4*)&As[lin + c * 4096] = pa;
      *(int32x4*)&Bs[lin + c * 4096] = pb;
    }
    __syncthreads();
    int32x4 afrag[4], bfrag[4];
#pragma unroll
    for (int i = 0; i < 4; ++i)
      afrag[i] = *(const int32x4*)&As[(wm + i * 16 + r) * 64 + quad * 16];
#pragma unroll
    for (int j = 0; j < 4; ++j)
      bfrag[j] = *(const int32x4*)&Bs[(wn + j * 16 + r) * 64 + quad * 16];
#pragma unroll
    for (int i = 0; i < 4; ++i)
#pragma unroll
      for (int j = 0; j < 4; ++j)
        acc[i][j] = __builtin_amdgcn_mfma_i32_16x16x64_i8(afrag[i], bfrag[j],
                                                          acc[i][j], 0, 0, 0);
    __syncthreads();
  }
  float swj[4], zpj[4], bj[4];
#pragma unroll
  for (int j = 0; j < 4; ++j) {
    int gc = col0 + wn + j * 16 + r;
    swj[j] = s_w[gc];
    zpj[j] = (float)zp_w[gc];
    bj[j] = bias[gc];
  }
#pragma unroll
  for (int i = 0; i < 4; ++i) {
#pragma unroll
    for (int t = 0; t < 4; ++t) {
      int gr = row0 + wm + i * 16 + quad * 4 + t;
      float siv = s_in[gr];
      float suv = sum_in[gr];
      float* orow = out + (size_t)gr * N + col0 + wn + r;
#pragma unroll
      for (int j = 0; j < 4; ++j) {
        float v = ((float)acc[i][j][t] + suv * zpj[j]) * (siv * swj[j]) + bj[j];
        orow[j * 16] = v;
      }
    }
  }
}

extern "C" void kernel_launch(void* const* d_in, const int* in_sizes, int n_in,
                              void* d_out, int out_size, void* d_ws, size_t ws_size,
                              hipStream_t stream) {
  const int* x_q = (const int*)d_in[0];
  const int* w_q = (const int*)d_in[1];
  const float* bias = (const float*)d_in[2];
  const float* s_in = (const float*)d_in[3];
  const float* s_w = (const float*)d_in[4];
  const float* sum_in = (const float*)d_in[5];
  const int* zp_w = (const int*)d_in[6];
  float* out = (float*)d_out;

  const int M = in_sizes[3];
  const int N = in_sizes[2];
  const int K = in_sizes[0] / M;

  const size_t needA = (size_t)M * K;
  const size_t needB = (size_t)N * K;

  if (ws_size >= needA + needB && (M % BM) == 0 && (N % BN) == 0 &&
      (K % BK) == 0 && (K / BK) >= 2) {
    uint8_t* A8 = (uint8_t*)d_ws;
    uint8_t* B8 = A8 + needA;
    const int nA4 = (int)(needA / 4);
    const int nTot4 = (int)((needA + needB) / 4);
    int nblk = (nTot4 + 255) / 256;
    if (nblk > 2048) nblk = 2048;
    pack_kernel<<<nblk, 256, 0, stream>>>(x_q, w_q, A8, B8, nA4, nTot4);
    dim3 grid(N / BN, M / BM), block(256);
    w8a8_gemm<<<grid, block, 0, stream>>>(A8, B8, bias, s_in, s_w, sum_in,
                                          zp_w, out, M, N, K);
  } else {
    dim3 grid(N / 128, M / 128), block(256);
    w8a8_gemm_fallback<<<grid, block, 0, stream>>>(x_q, w_q, bias, s_in, s_w,
                                                   sum_in, zp_w, out, M, N, K);
  }
}

// Round 6
// 398.417 us; speedup vs baseline: 1.0202x; 1.0202x over previous
//
#include <hip/hip_runtime.h>
#include <stdint.h>

// W8A8 int8 GEMM + dequant epilogue, MI355X gfx950.
// R12: TLP round. R6-R11 post-mortems: MFMA-busy time is constant 62us
// (the i8 floor) across ALL pipeline structures (drain0/counted/phased);
// stall arrangement never moved it. The only mechanism that feeds the
// matrix pipe during a block's barrier-drain is OTHER resident blocks
// (m114 implicit overlap), and every variant so far was LDS-capped at
// <=2 blocks/CU. This round: BM=BN=BK=128 single-buffer = 32 KiB LDS
// -> 5 blocks/CU (20 waves). 4 waves 2x2, wave 64x64, acc 2x2 of 32x32,
// 88 VGPR (measured R11) -> 5 waves/SIMD fits reg budget (440<=512).
// Per-CU pipe budget: LDS-read 768 cyc vs MFMA 585 cyc per tile-block ->
// LDS-pipe-bound ceiling ~76% MfmaUtil; TLP should carry us toward it.
// BK=128 8-chunk XOR swizzle, measured conflict-free R3/R5/R6/R10/R11.
// out[m,n] = (sum_k A*W + sum_input[m]*zp_w[n]) * si[m]*sw[n] + bias[n]

#define BM 128
#define BN 128
#define BK 128

typedef __attribute__((ext_vector_type(4))) int int32x4;
typedef __attribute__((ext_vector_type(16))) int int32x16;

__device__ __forceinline__ void async_copy16(const uint8_t* g, uint8_t* l) {
  __builtin_amdgcn_global_load_lds(
      (const __attribute__((address_space(1))) uint32_t*)(const void*)g,
      (__attribute__((address_space(3))) uint32_t*)l,
      16, 0, 0);
}

// Coalesced pack, grid-stride: one int32x4 (4 int8-as-int32) -> one uint32.
__global__ __launch_bounds__(256) void pack_kernel(
    const int* __restrict__ A, const int* __restrict__ B,
    uint8_t* __restrict__ A8, uint8_t* __restrict__ B8,
    int nA4, int nTot4) {
  const int stride = gridDim.x * blockDim.x;
  for (int t = blockIdx.x * blockDim.x + threadIdx.x; t < nTot4; t += stride) {
    const int32x4* src;
    uint32_t* dst;
    if (t < nA4) {
      src = (const int32x4*)A + t;
      dst = (uint32_t*)A8 + t;
    } else {
      int u = t - nA4;
      src = (const int32x4*)B + u;
      dst = (uint32_t*)B8 + u;
    }
    int32x4 v = __builtin_nontemporal_load(src);  // read-once stream
    *dst = (uint32_t)(v.x & 255) | ((uint32_t)(v.y & 255) << 8) |
           ((uint32_t)(v.z & 255) << 16) | ((uint32_t)(v.w & 255) << 24);
  }
}

// Stage one 128x128 A tile (4 issues) + 128x128 B tile (4 issues).
// Thread: row_s = tid>>3 (0..31), slot cs = tid&7, global chunk
// cg = cs ^ ((tid>>4)&7); issue p covers rows [p*32, p*32+32).
// Invariant: LDS row r (128 B) slot cs holds global chunk cs ^ ((r>>1)&7).
// (Byte-identical to R11's stage; measured SQ_LDS_BANK_CONFLICT == 0.)
__device__ __forceinline__ void stage_tile(
    const uint8_t* Ab, const uint8_t* Bb, size_t sK, int k0,
    uint8_t* AsBuf, uint8_t* BsBuf, int ldst) {
#pragma unroll
  for (int p = 0; p < 4; ++p)
    async_copy16(Ab + (size_t)(p * 32) * sK + k0, AsBuf + p * 4096 + ldst);
#pragma unroll
  for (int p = 0; p < 4; ++p)
    async_copy16(Bb + (size_t)(p * 32) * sK + k0, BsBuf + p * 4096 + ldst);
}

__global__ __launch_bounds__(256, 4) void w8a8_gemm(
    const uint8_t* __restrict__ A8, const uint8_t* __restrict__ B8,
    const float* __restrict__ bias,
    const float* __restrict__ s_in,
    const float* __restrict__ s_w,
    const float* __restrict__ sum_in,
    const int* __restrict__ zp_w,
    float* __restrict__ out,
    int M, int N, int K) {
  __shared__ uint8_t As[BM * BK];  // 16 KiB
  __shared__ uint8_t Bs[BN * BK];  // 16 KiB  -> 32 KiB total, 5 blocks/CU

  const int tid = threadIdx.x;
  const int bm = blockIdx.y, bn = blockIdx.x;  // plain 2D grid
  const int row0 = bm * BM, col0 = bn * BN;

  const int wave = tid >> 6, lane = tid & 63;
  const int m32 = lane & 31, half = lane >> 5;
  const int wm = (wave >> 1) * 64;  // 2 wave-rows of 64
  const int wn = (wave & 1) * 64;   // 2 wave-cols of 64
  const size_t sK = (size_t)K;

  // staging geometry (see stage_tile comment)
  const int row_s = tid >> 3;                   // 0..31
  const int cg = (tid & 7) ^ ((tid >> 4) & 7);
  const int ldst = tid * 16;

  const uint8_t* Ab = A8 + (size_t)(row0 + row_s) * sK + cg * 16;
  const uint8_t* Bb = B8 + (size_t)(col0 + row_s) * sK + cg * 16;

  int32x16 acc[2][2] = {};

  const int swzr = (m32 >> 1) & 7;
  for (int k0 = 0; k0 < K; k0 += BK) {
    stage_tile(Ab, Bb, sK, k0, As, Bs, ldst);
    __syncthreads();  // drains vmcnt(0); other resident blocks cover this

#pragma unroll
    for (int ks = 0; ks < 4; ++ks) {
      const int gran = ((ks * 2 + half) ^ swzr) * 16;
      int32x4 afrag[2], bfrag[2];
#pragma unroll
      for (int i = 0; i < 2; ++i)
        afrag[i] = *(const int32x4*)&As[(wm + i * 32 + m32) * BK + gran];
#pragma unroll
      for (int j = 0; j < 2; ++j)
        bfrag[j] = *(const int32x4*)&Bs[(wn + j * 32 + m32) * BK + gran];
#pragma unroll
      for (int i = 0; i < 2; ++i)
#pragma unroll
        for (int j = 0; j < 2; ++j)
          acc[i][j] = __builtin_amdgcn_mfma_i32_32x32x32_i8(
              afrag[i], bfrag[j], acc[i][j], 0, 0, 0);
    }
    __syncthreads();
  }

  // Epilogue: 32x32 C/D layout col=lane&31, row=(reg&3)+8*(reg>>2)+4*(lane>>5).
  float swj[2], zpj[2], bj[2];
#pragma unroll
  for (int j = 0; j < 2; ++j) {
    int gc = col0 + wn + j * 32 + m32;
    swj[j] = s_w[gc];
    zpj[j] = (float)zp_w[gc];
    bj[j] = bias[gc];
  }
#pragma unroll
  for (int i = 0; i < 2; ++i) {
#pragma unroll
    for (int reg = 0; reg < 16; ++reg) {
      int gr = row0 + wm + i * 32 + (reg & 3) + 8 * (reg >> 2) + 4 * half;
      float siv = s_in[gr];
      float suv = sum_in[gr];
      float* orow = out + (size_t)gr * N + col0 + wn + m32;
#pragma unroll
      for (int j = 0; j < 2; ++j) {
        float v = ((float)acc[i][j][reg] + suv * zpj[j]) * (siv * swj[j]) + bj[j];
        __builtin_nontemporal_store(v, &orow[j * 32]);
      }
    }
  }
}

// Fallback (ws too small): unpacked int32 inputs, BK=64, VALU pack + ds_write.
__global__ __launch_bounds__(256) void w8a8_gemm_fallback(
    const int* __restrict__ A32, const int* __restrict__ B32,
    const float* __restrict__ bias,
    const float* __restrict__ s_in,
    const float* __restrict__ s_w,
    const float* __restrict__ sum_in,
    const int* __restrict__ zp_w,
    float* __restrict__ out,
    int M, int N, int K) {
  __shared__ uint8_t As[128 * 64];
  __shared__ uint8_t Bs[128 * 64];
  const int tid = threadIdx.x;
  const int bm = blockIdx.y, bn = blockIdx.x;
  const int row0 = bm * 128, col0 = bn * 128;
  const int wave = tid >> 6, lane = tid & 63;
  const int quad = lane >> 4, r = lane & 15;
  const int wm = (wave >> 1) * 64, wn = (wave & 1) * 64;
  const int lin = tid * 16;
  const int srow = lin >> 6;
  const int scol = lin & 63;
  const size_t sK = (size_t)K;
  int32x4 acc[4][4] = {};
  for (int k0 = 0; k0 < K; k0 += 64) {
#pragma unroll
    for (int c = 0; c < 2; ++c) {
      const int* ag = A32 + (size_t)(row0 + srow + c * 64) * sK + k0 + scol;
      const int* bg = B32 + (size_t)(col0 + srow + c * 64) * sK + k0 + scol;
      int32x4 pa, pb;
#pragma unroll
      for (int q = 0; q < 4; ++q) {
        int4 va = ((const int4*)ag)[q];
        int4 vb = ((const int4*)bg)[q];
        pa[q] = (int)((uint32_t)(va.x & 255) | ((uint32_t)(va.y & 255) << 8) |
                      ((uint32_t)(va.z & 255) << 16) | ((uint32_t)(va.w & 255) << 24));
        pb[q] = (int)((uint32_t)(vb.x & 255) | ((uint32_t)(vb.y & 255) << 8) |
                      ((uint32_t)(vb.z & 255) << 16) | ((uint32_t)(vb.w & 255) << 24));
      }
      *(int32x4*)&As[lin + c * 4096] = pa;
      *(int32x4*)&Bs[lin + c * 4096] = pb;
    }
    __syncthreads();
    int32x4 afrag[4], bfrag[4];
#pragma unroll
    for (int i = 0; i < 4; ++i)
      afrag[i] = *(const int32x4*)&As[(wm + i * 16 + r) * 64 + quad * 16];
#pragma unroll
    for (int j = 0; j < 4; ++j)
      bfrag[j] = *(const int32x4*)&Bs[(wn + j * 16 + r) * 64 + quad * 16];
#pragma unroll
    for (int i = 0; i < 4; ++i)
#pragma unroll
      for (int j = 0; j < 4; ++j)
        acc[i][j] = __builtin_amdgcn_mfma_i32_16x16x64_i8(afrag[i], bfrag[j],
                                                          acc[i][j], 0, 0, 0);
    __syncthreads();
  }
  float swj[4], zpj[4], bj[4];
#pragma unroll
  for (int j = 0; j < 4; ++j) {
    int gc = col0 + wn + j * 16 + r;
    swj[j] = s_w[gc];
    zpj[j] = (float)zp_w[gc];
    bj[j] = bias[gc];
  }
#pragma unroll
  for (int i = 0; i < 4; ++i) {
#pragma unroll
    for (int t = 0; t < 4; ++t) {
      int gr = row0 + wm + i * 16 + quad * 4 + t;
      float siv = s_in[gr];
      float suv = sum_in[gr];
      float* orow = out + (size_t)gr * N + col0 + wn + r;
#pragma unroll
      for (int j = 0; j < 4; ++j) {
        float v = ((float)acc[i][j][t] + suv * zpj[j]) * (siv * swj[j]) + bj[j];
        orow[j * 16] = v;
      }
    }
  }
}

extern "C" void kernel_launch(void* const* d_in, const int* in_sizes, int n_in,
                              void* d_out, int out_size, void* d_ws, size_t ws_size,
                              hipStream_t stream) {
  const int* x_q = (const int*)d_in[0];
  const int* w_q = (const int*)d_in[1];
  const float* bias = (const float*)d_in[2];
  const float* s_in = (const float*)d_in[3];
  const float* s_w = (const float*)d_in[4];
  const float* sum_in = (const float*)d_in[5];
  const int* zp_w = (const int*)d_in[6];
  float* out = (float*)d_out;

  const int M = in_sizes[3];
  const int N = in_sizes[2];
  const int K = in_sizes[0] / M;

  const size_t needA = (size_t)M * K;
  const size_t needB = (size_t)N * K;

  if (ws_size >= needA + needB && (M % BM) == 0 && (N % BN) == 0 &&
      (K % BK) == 0) {
    uint8_t* A8 = (uint8_t*)d_ws;
    uint8_t* B8 = A8 + needA;
    const int nA4 = (int)(needA / 4);
    const int nTot4 = (int)((needA + needB) / 4);
    int nblk = (nTot4 + 255) / 256;
    if (nblk > 2048) nblk = 2048;
    pack_kernel<<<nblk, 256, 0, stream>>>(x_q, w_q, A8, B8, nA4, nTot4);
    dim3 grid(N / BN, M / BM), block(256);
    w8a8_gemm<<<grid, block, 0, stream>>>(A8, B8, bias, s_in, s_w, sum_in,
                                          zp_w, out, M, N, K);
  } else {
    dim3 grid(N / 128, M / 128), block(256);
    w8a8_gemm_fallback<<<grid, block, 0, stream>>>(x_q, w_q, bias, s_in, s_w,
                                                   sum_in, zp_w, out, M, N, K);
  }
}